// Round 1
// baseline (314.144 us; speedup 1.0000x reference)
//
#include <hip/hip_runtime.h>

#define B_SZ 32
#define L 4096
#define H 512
#define P 384
#define V 32
#define OUT_LEN 16
#define NC 8
#define CHUNK 510
#define T0 4080   // NC*CHUNK; last 16 steps handled in combine kernel

// ---- workspace layout (float offsets) ----
#define OFF_LBAR 0                                   // [P][2]  fp32 Lambda_bar
#define OFF_M    (2*P)                               // [V][P][2] token->Bu_bar table
#define OFF_PART (OFF_M + 2*V*P)                     // [B][NC][P][2] chunk partials
#define OFF_XS   (OFF_PART + 2*B_SZ*NC*P)            // [B][P][OUT_LEN][2] last-16 states
#define OFF_YT   (OFF_XS + 2*B_SZ*P*OUT_LEN)         // [H][512] y transposed (r = b*16+l)
// total = 615168 + 262144 = 877312 floats = 3.51 MB

// K1: Lambda_bar (double), M table, init d_out with b2.
__global__ __launch_bounds__(256) void k_prep(
    const float* __restrict__ embed, const float* __restrict__ Lre,
    const float* __restrict__ Lim, const float* __restrict__ Bre,
    const float* __restrict__ Bim, const float* __restrict__ log_step,
    const float* __restrict__ b2, float* __restrict__ ws, float* __restrict__ out)
{
    int id = blockIdx.x * 256 + threadIdx.x;
    if (id < B_SZ * OUT_LEN * V) out[id] = b2[id & (V - 1)];  // out init = b2
    if (id >= V * P) return;
    int v = id / P, p = id - v * P;

    double dstep = exp((double)log_step[p]);
    double lre = (double)Lre[p], lim = (double)Lim[p];
    double are = lre * dstep, aim = lim * dstep;
    double mag = exp(are);
    double lbr = mag * cos(aim), lbi = mag * sin(aim);
    if (v == 0) { ws[OFF_LBAR + 2*p] = (float)lbr; ws[OFF_LBAR + 2*p + 1] = (float)lbi; }

    // coef = (Lbar - 1) / Lam   (double; |Lam_re| >= 0.001 so safe)
    double nr = lbr - 1.0, ni = lbi;
    double den = lre*lre + lim*lim;
    double cr = (nr*lre + ni*lim) / den;
    double ci = (ni*lre - nr*lim) / den;

    const float* br = Bre + p * H;
    const float* bi = Bim + p * H;
    const float* ev = embed + v * H;
    float dr = 0.f, di = 0.f;
    #pragma unroll 4
    for (int h = 0; h < H; h += 4) {
        float4 e4 = *(const float4*)(ev + h);
        float4 r4 = *(const float4*)(br + h);
        float4 i4 = *(const float4*)(bi + h);
        dr += r4.x*e4.x + r4.y*e4.y + r4.z*e4.z + r4.w*e4.w;
        di += i4.x*e4.x + i4.y*e4.y + i4.z*e4.z + i4.w*e4.w;
    }
    double mr = cr*(double)dr - ci*(double)di;
    double mi = cr*(double)di + ci*(double)dr;
    ws[OFF_M + 2*(v*P + p)]     = (float)mr;
    ws[OFF_M + 2*(v*P + p) + 1] = (float)mi;
}

// K2: chunked scan. block = (chunk, p-half) x batch; thread = one p.
// partial[b][c][p] = sum_{i<CHUNK} Lbar^{CHUNK-1-i} * M[tok[b, c*CHUNK+i]][p]
__global__ __launch_bounds__(192) void k_scan(
    const int* __restrict__ tokens, const float* __restrict__ ws,
    float* __restrict__ partial)
{
    __shared__ float2 sM[V * 192];   // 49152 B: half of M (192 p values)
    int c  = blockIdx.x >> 1;
    int ph = blockIdx.x & 1;
    int b  = blockIdx.y;
    int tid = threadIdx.x;

    const float2* Mg = (const float2*)(ws + OFF_M);
    for (int v = 0; v < V; ++v)
        sM[v * 192 + tid] = Mg[v * P + ph * 192 + tid];
    __syncthreads();

    int p = ph * 192 + tid;
    float Lr = ws[OFF_LBAR + 2*p], Li = ws[OFF_LBAR + 2*p + 1];
    float ar = 0.f, ai = 0.f;
    const int* tk = tokens + b * L + c * CHUNK;   // uniform -> scalar loads
    #pragma unroll 2
    for (int i = 0; i < CHUNK; ++i) {
        int t = tk[i];
        float2 m = sM[t * 192 + tid];
        float nar = fmaf(Lr, ar, fmaf(-Li, ai, m.x));
        float nai = fmaf(Lr, ai, fmaf( Li, ar, m.y));
        ar = nar; ai = nai;
    }
    int idx = (b * NC + c) * P + p;
    partial[2*idx] = ar; partial[2*idx + 1] = ai;
}

// K3: combine chunk partials (double), run the 16 tail steps, store xs.
__global__ __launch_bounds__(384) void k_combine(
    const int* __restrict__ tokens, const float* __restrict__ Lre,
    const float* __restrict__ Lim, const float* __restrict__ log_step,
    float* __restrict__ ws)
{
    int p = threadIdx.x, b = blockIdx.x;
    double dstep = exp((double)log_step[p]);
    double are = (double)Lre[p] * dstep;
    double aim = (double)Lim[p] * dstep;
    double mag = exp(are);
    double lbr = mag * cos(aim), lbi = mag * sin(aim);
    // W = Lbar^CHUNK, computed in double (phase exact to ~1e-12)
    double wmag = exp((double)CHUNK * are);
    double wang = (double)CHUNK * aim;
    double wr = wmag * cos(wang), wi = wmag * sin(wang);

    double xr = 0.0, xi = 0.0;
    const float* pp = ws + OFF_PART + 2*(b * NC * P + p);
    for (int c = 0; c < NC; ++c) {
        double pr  = (double)pp[2*c*P];
        double pim = (double)pp[2*c*P + 1];
        double txr = wr*xr - wi*xi + pr;
        double txi = wr*xi + wi*xr + pim;
        xr = txr; xi = txi;
    }
    // tail: t = T0 .. L-1, store each state
    const float* M = ws + OFF_M;
    float* xs = ws + OFF_XS + (b * P + p) * 2 * OUT_LEN;
    for (int j = 0; j < OUT_LEN; ++j) {
        int t = tokens[b * L + T0 + j];
        double mr = (double)M[2*(t*P + p)];
        double mi = (double)M[2*(t*P + p) + 1];
        double txr = lbr*xr - lbi*xi + mr;
        double txi = lbr*xi + lbi*xr + mi;
        xr = txr; xi = txi;
        xs[2*j] = (float)xr; xs[2*j + 1] = (float)xi;
    }
}

// K4: y[b,l,h] = 2*Re(sum_p Cc[h,p]*xs[b,l,p]) + u*D; write transposed Yt[h][r].
// block = (b, l-half, h-half); thread = h, 8 l-accumulators; xs reads are uniform.
__global__ __launch_bounds__(256) void k_y(
    const int* __restrict__ tokens, const float* __restrict__ embed,
    const float* __restrict__ Cre, const float* __restrict__ Cim,
    const float* __restrict__ D, float* __restrict__ ws)
{
    int hh = blockIdx.x & 1;
    int lh = (blockIdx.x >> 1) & 1;
    int b  = blockIdx.x >> 2;
    int h  = hh * 256 + threadIdx.x;

    const float* xp = ws + OFF_XS + b * (P * 2 * OUT_LEN) + lh * 16;
    const float* cr = Cre + h * P;
    const float* ci = Cim + h * P;
    float acc[8];
    #pragma unroll
    for (int i = 0; i < 8; ++i) acc[i] = 0.f;
    #pragma unroll 4
    for (int p = 0; p < P; ++p) {
        float cv = cr[p], dv = ci[p];            // per-thread contiguous
        const float* x2 = xp + p * (2 * OUT_LEN); // uniform -> s_load
        #pragma unroll
        for (int i = 0; i < 8; ++i)
            acc[i] += cv * x2[2*i] - dv * x2[2*i + 1];
    }
    float dh = D[h];
    int r0 = b * OUT_LEN + lh * 8;
    float* Yt = ws + OFF_YT + h * 512 + r0;
    #pragma unroll
    for (int i = 0; i < 8; ++i) {
        int t = tokens[b * L + T0 + lh * 8 + i];  // uniform
        Yt[i] = 2.f * acc[i] + embed[t * H + h] * dh;
    }
}

// K5: out = relu(Y@W1 + b1) @ W2 + b2 (b2 pre-initialized by k_prep; atomic add
// of per-jhalf partials). block = (rgroup of 8, j-half); thread = j.
__global__ __launch_bounds__(256) void k_mlp(
    const float* __restrict__ W1, const float* __restrict__ b1,
    const float* __restrict__ W2, const float* __restrict__ ws,
    float* __restrict__ out)
{
    int jh = blockIdx.x & 1;
    int g  = blockIdx.x >> 1;      // 0..63 row-groups of 8
    int j  = jh * 256 + threadIdx.x;
    int r0 = g * 8;
    const float* Yt = ws + OFF_YT;
    float bb = b1[j];
    float acc[8];
    #pragma unroll
    for (int i = 0; i < 8; ++i) acc[i] = bb;
    #pragma unroll 2
    for (int k = 0; k < H; ++k) {
        float w = W1[k * H + j];               // coalesced
        const float* yr = Yt + k * 512 + r0;   // uniform, 8 contiguous -> s_load
        #pragma unroll
        for (int i = 0; i < 8; ++i) acc[i] = fmaf(yr[i], w, acc[i]);
    }
    __shared__ float sh[8][256];
    #pragma unroll
    for (int i = 0; i < 8; ++i) sh[i][threadIdx.x] = fmaxf(acc[i], 0.f);
    __syncthreads();
    // 256 threads = 8 rows x 32 outputs; reduce over this block's 256 j values
    int ri = threadIdx.x >> 5, o = threadIdx.x & 31;
    float s = 0.f;
    const float* w2 = W2 + (jh * 256) * V + o;
    for (int jj = 0; jj < 256; ++jj)
        s = fmaf(sh[ri][jj], w2[jj * V], s);
    atomicAdd(&out[(r0 + ri) * V + o], s);
}

extern "C" void kernel_launch(void* const* d_in, const int* in_sizes, int n_in,
                              void* d_out, int out_size, void* d_ws, size_t ws_size,
                              hipStream_t stream)
{
    const int*   tokens = (const int*)d_in[0];
    const float* embed  = (const float*)d_in[1];
    const float* Lre    = (const float*)d_in[2];
    const float* Lim    = (const float*)d_in[3];
    const float* Bre    = (const float*)d_in[4];
    const float* Bim    = (const float*)d_in[5];
    const float* Cre    = (const float*)d_in[6];
    const float* Cim    = (const float*)d_in[7];
    const float* D      = (const float*)d_in[8];
    const float* lstep  = (const float*)d_in[9];
    const float* W1     = (const float*)d_in[10];
    const float* b1     = (const float*)d_in[11];
    const float* W2     = (const float*)d_in[12];
    const float* b2     = (const float*)d_in[13];
    float* out = (float*)d_out;
    float* ws  = (float*)d_ws;

    k_prep   <<<64, 256, 0, stream>>>(embed, Lre, Lim, Bre, Bim, lstep, b2, ws, out);
    k_scan   <<<dim3(2 * NC, B_SZ), 192, 0, stream>>>(tokens, ws, ws + OFF_PART);
    k_combine<<<B_SZ, P, 0, stream>>>(tokens, Lre, Lim, lstep, ws);
    k_y      <<<128, 256, 0, stream>>>(tokens, embed, Cre, Cim, D, ws);
    k_mlp    <<<128, 256, 0, stream>>>(W1, b1, W2, ws, out);
}

// Round 2
// 228.198 us; speedup vs baseline: 1.3766x; 1.3766x over previous
//
#include <hip/hip_runtime.h>

#define B_SZ 32
#define L 4096
#define H 512
#define P 384
#define V 32
#define OUT_LEN 16
#define NC 16
#define CHUNK 255
#define T0 4080   // NC*CHUNK

// ---- ws layout (float offsets). doubles first (8B aligned at 0).
#define OFF_DBL   0           // [P][6] doubles: lbr,lbi,wr,wi,cr,ci = 4608 floats
#define OFF_LBARF 4608        // [P][2] float Lambda_bar
#define OFF_M     5376        // [V][P][2] token->Bu_bar table
#define OFF_CT    29952       // [P][2][H] transposed C
#define OFF_YT    423168      // [512 r][512 h] y (r = b*16+l)
#define OFF_PART  685312      // [B][NC][P][2] chunk partials
#define OFF_XS    1078528     // [B][P][16][2] last-16 states
#define OFF_HP    685312      // alias over PART+XS (dead by then): [4][512][512]
// max end = OFF_HP + 1048576 = 1733888 floats = 6.94 MB

// K1: blocks 0..191 transpose C into CT; blocks 192..193 compute per-p double
// constants (Lambda_bar, W=Lbar^CHUNK, coef=(Lbar-1)/Lam).
__global__ __launch_bounds__(256) void k_init(
    const float* __restrict__ Lre, const float* __restrict__ Lim,
    const float* __restrict__ log_step,
    const float* __restrict__ Cre, const float* __restrict__ Cim,
    float* __restrict__ ws)
{
    int bx = blockIdx.x, tid = threadIdx.x;
    if (bx < 192) {
        __shared__ float sre[32][33], sim[32][33];
        int tp = bx >> 4, th = bx & 15;          // 12 p-tiles x 16 h-tiles
        int col = tid & 31, r0 = tid >> 5;       // 8 rows per pass
        #pragma unroll
        for (int it = 0; it < 4; ++it) {
            int row = r0 + 8 * it;
            int h = th * 32 + row, p = tp * 32 + col;
            sre[col][row] = Cre[h * P + p];      // coalesced over col
            sim[col][row] = Cim[h * P + p];
        }
        __syncthreads();
        #pragma unroll
        for (int it = 0; it < 4; ++it) {
            int pl = r0 + 8 * it;
            int p = tp * 32 + pl, h = th * 32 + col;
            ws[OFF_CT + (2 * p) * H + h]     = sre[pl][col];   // coalesced over col
            ws[OFF_CT + (2 * p + 1) * H + h] = sim[pl][col];
        }
    } else {
        int p = (bx - 192) * 256 + tid;
        if (p >= P) return;
        double dstep = exp((double)log_step[p]);
        double are = (double)Lre[p] * dstep, aim = (double)Lim[p] * dstep;
        double mag = exp(are);
        double lbr = mag * cos(aim), lbi = mag * sin(aim);
        double wmag = exp((double)CHUNK * are);
        double wang = (double)CHUNK * aim;
        double wr = wmag * cos(wang), wi = wmag * sin(wang);
        double lre = (double)Lre[p], lim = (double)Lim[p];
        double nr = lbr - 1.0, ni = lbi;
        double den = lre * lre + lim * lim;
        double cr = (nr * lre + ni * lim) / den, ci = (ni * lre - nr * lim) / den;
        double* d = (double*)ws + p * 6;
        d[0] = lbr; d[1] = lbi; d[2] = wr; d[3] = wi; d[4] = cr; d[5] = ci;
        ws[OFF_LBARF + 2 * p]     = (float)lbr;
        ws[OFF_LBARF + 2 * p + 1] = (float)lbi;
    }
}

// K2: M table, one wave per (v,p). 3072 blocks x 256.
__global__ __launch_bounds__(256) void k_mtab(
    const float* __restrict__ embed, const float* __restrict__ Bre,
    const float* __restrict__ Bim, float* __restrict__ ws)
{
    int wid = blockIdx.x * 4 + (threadIdx.x >> 6);   // [0, 12288)
    int lane = threadIdx.x & 63;
    int v = wid / P, p = wid - v * P;
    const float4* ev = (const float4*)(embed + v * H) + lane * 2;
    const float4* br = (const float4*)(Bre + p * H) + lane * 2;
    const float4* bi = (const float4*)(Bim + p * H) + lane * 2;
    float dr = 0.f, di = 0.f;
    #pragma unroll
    for (int q = 0; q < 2; ++q) {
        float4 e = ev[q], r = br[q], i = bi[q];
        dr += r.x * e.x + r.y * e.y + r.z * e.z + r.w * e.w;
        di += i.x * e.x + i.y * e.y + i.z * e.z + i.w * e.w;
    }
    #pragma unroll
    for (int off = 32; off; off >>= 1) {
        dr += __shfl_down(dr, off);
        di += __shfl_down(di, off);
    }
    if (lane == 0) {
        const double* d = (const double*)ws + p * 6;
        double cr = d[4], ci = d[5];
        double mr = cr * (double)dr - ci * (double)di;
        double mi = cr * (double)di + ci * (double)dr;
        ws[OFF_M + (v * P + p) * 2]     = (float)mr;
        ws[OFF_M + (v * P + p) * 2 + 1] = (float)mi;
    }
}

// K3: chunked scan. grid (c*2+ph : 32, b : 32), 192 threads (one p each).
__global__ __launch_bounds__(192) void k_scan(
    const int* __restrict__ tokens, const float* __restrict__ ws,
    float* __restrict__ part)
{
    __shared__ float2 sM[V * 192];   // 48 KB -> 3 blocks/CU
    int x = blockIdx.x, b = blockIdx.y;
    int c = x >> 1, ph = x & 1;
    int tid = threadIdx.x;
    const float2* Mg = (const float2*)(ws + OFF_M);
    #pragma unroll
    for (int v = 0; v < V; ++v)
        sM[v * 192 + tid] = Mg[v * P + ph * 192 + tid];
    int p = ph * 192 + tid;
    float Lr = ws[OFF_LBARF + 2 * p], Li = ws[OFF_LBARF + 2 * p + 1];
    __syncthreads();
    float ar = 0.f, ai = 0.f;
    const int* tk = tokens + b * L + c * CHUNK;
    #pragma unroll 3
    for (int i = 0; i < CHUNK; ++i) {
        int t = tk[i];
        float2 m = sM[t * 192 + tid];
        float nar = fmaf(Lr, ar, fmaf(-Li, ai, m.x));
        float nai = fmaf(Lr, ai, fmaf( Li, ar, m.y));
        ar = nar; ai = nai;
    }
    float* pt = part + ((b * NC + c) * P + p) * 2;
    pt[0] = ar; pt[1] = ai;
}

// K4: combine partials (double) + 16 tail steps. thread = (b,p). 48 blocks.
__global__ __launch_bounds__(256) void k_combine(
    const int* __restrict__ tokens, float* __restrict__ ws)
{
    int id = blockIdx.x * 256 + threadIdx.x;   // exactly 12288
    int b = id / P, p = id - b * P;
    const double* d = (const double*)ws + p * 6;
    double lbr = d[0], lbi = d[1], wr = d[2], wi = d[3];
    double xr = 0.0, xi = 0.0;
    const float* pp = ws + OFF_PART + (b * NC * P + p) * 2;
    #pragma unroll
    for (int c = 0; c < NC; ++c) {
        double pr = (double)pp[c * P * 2], pi = (double)pp[c * P * 2 + 1];
        double tr = wr * xr - wi * xi + pr;
        double ti = wr * xi + wi * xr + pi;
        xr = tr; xi = ti;
    }
    const float* M = ws + OFF_M;
    float* xs = ws + OFF_XS + (b * P + p) * OUT_LEN * 2;
    const int* tk = tokens + b * L + T0;
    #pragma unroll
    for (int j = 0; j < OUT_LEN; ++j) {
        int t = tk[j];
        double mr = (double)M[(t * P + p) * 2], mi = (double)M[(t * P + p) * 2 + 1];
        double tr = lbr * xr - lbi * xi + mr;
        double ti = lbr * xi + lbi * xr + mi;
        xr = tr; xi = ti;
        xs[2 * j] = (float)xr; xs[2 * j + 1] = (float)xi;
    }
}

// K5: Yt[r][h] = 2*Re(C x) + u*D. grid (lp*2+hh : 16, b : 32) x 256. Also zeroes out.
__global__ __launch_bounds__(256) void k_y(
    const int* __restrict__ tokens, const float* __restrict__ embed,
    const float* __restrict__ D, float* __restrict__ ws, float* __restrict__ out)
{
    int x = blockIdx.x, b = blockIdx.y;
    int lp = x >> 1, hh = x & 1;
    int tid = threadIdx.x;
    int h = hh * 256 + tid;
    int g = (b * 16 + x) * 256 + tid;
    if (g < B_SZ * OUT_LEN * V) out[g] = 0.f;   // zero d_out for K7's atomics

    const float* ct = ws + OFF_CT;
    float a0 = 0.f, a1 = 0.f;
    #pragma unroll 2
    for (int p = 0; p < P; ++p) {
        float cre = ct[(2 * p) * H + h];          // coalesced
        float cim = ct[(2 * p + 1) * H + h];
        const float* x4 = ws + OFF_XS + (b * P + p) * 32 + lp * 4;  // uniform
        float x0r = x4[0], x0i = x4[1], x1r = x4[2], x1i = x4[3];
        a0 = fmaf(cre, x0r, fmaf(-cim, x0i, a0));
        a1 = fmaf(cre, x1r, fmaf(-cim, x1i, a1));
    }
    int l0 = lp * 2;
    int t0 = tokens[b * L + T0 + l0], t1 = tokens[b * L + T0 + l0 + 1];
    float dh = D[h];
    ws[OFF_YT + (b * OUT_LEN + l0) * H + h]     = 2.f * a0 + embed[t0 * H + h] * dh;
    ws[OFF_YT + (b * OUT_LEN + l0 + 1) * H + h] = 2.f * a1 + embed[t1 * H + h] * dh;
}

// K6: GEMM1 partials, 4-way k-split. 512 blocks x 256. Hp[kc][r][j].
__global__ __launch_bounds__(256) void k_fc1(
    const float* __restrict__ W1, const float* __restrict__ yt,
    float* __restrict__ hp)
{
    int bx = blockIdx.x;
    int rg = bx >> 3, jh = (bx >> 2) & 1, kc = bx & 3;
    int j = jh * 256 + threadIdx.x;
    int r0 = rg * 8;
    float acc[8] = {0, 0, 0, 0, 0, 0, 0, 0};
    int k0 = kc * 128;
    #pragma unroll 2
    for (int k = k0; k < k0 + 128; ++k) {
        float w = W1[k * H + j];                 // coalesced
        const float* yr = yt + k;                // Yt[r][k]: uniform scalar loads
        #pragma unroll
        for (int i = 0; i < 8; ++i)
            acc[i] = fmaf(yr[(r0 + i) * H], w, acc[i]);
    }
    #pragma unroll
    for (int i = 0; i < 8; ++i)
        hp[(kc * 512 + r0 + i) * H + j] = acc[i];  // coalesced
}

// K7: reduce partials + bias + relu + GEMM2 + atomicAdd. 128 blocks x 256.
__global__ __launch_bounds__(256) void k_fc2(
    const float* __restrict__ b1, const float* __restrict__ W2,
    const float* __restrict__ b2, const float* __restrict__ hp,
    float* __restrict__ out)
{
    __shared__ float sh[8][256];
    int bx = blockIdx.x;
    int rg = bx >> 1, jh = bx & 1;
    int tid = threadIdx.x;
    int j = jh * 256 + tid;
    int r0 = rg * 8;
    float bb = b1[j];
    #pragma unroll
    for (int i = 0; i < 8; ++i) {
        int r = r0 + i;
        float s = bb + hp[r * H + j] + hp[(512 + r) * H + j]
                     + hp[(1024 + r) * H + j] + hp[(1536 + r) * H + j];
        sh[i][tid] = fmaxf(s, 0.f);
    }
    __syncthreads();
    int ri = tid >> 5, o = tid & 31;
    float s = (jh == 0) ? b2[o] : 0.f;
    #pragma unroll 4
    for (int jj = 0; jj < 256; ++jj)
        s = fmaf(sh[ri][jj], W2[(jh * 256 + jj) * V + o], s);  // coalesced, L2-hot
    atomicAdd(&out[(r0 + ri) * V + o], s);
}

extern "C" void kernel_launch(void* const* d_in, const int* in_sizes, int n_in,
                              void* d_out, int out_size, void* d_ws, size_t ws_size,
                              hipStream_t stream)
{
    const int*   tokens = (const int*)d_in[0];
    const float* embed  = (const float*)d_in[1];
    const float* Lre    = (const float*)d_in[2];
    const float* Lim    = (const float*)d_in[3];
    const float* Bre    = (const float*)d_in[4];
    const float* Bim    = (const float*)d_in[5];
    const float* Cre    = (const float*)d_in[6];
    const float* Cim    = (const float*)d_in[7];
    const float* D      = (const float*)d_in[8];
    const float* lstep  = (const float*)d_in[9];
    const float* W1     = (const float*)d_in[10];
    const float* b1     = (const float*)d_in[11];
    const float* W2     = (const float*)d_in[12];
    const float* b2     = (const float*)d_in[13];
    float* out = (float*)d_out;
    float* ws  = (float*)d_ws;

    k_init   <<<194, 256, 0, stream>>>(Lre, Lim, lstep, Cre, Cim, ws);
    k_mtab   <<<3072, 256, 0, stream>>>(embed, Bre, Bim, ws);
    k_scan   <<<dim3(32, 32), 192, 0, stream>>>(tokens, ws, ws + OFF_PART);
    k_combine<<<48, 256, 0, stream>>>(tokens, ws);
    k_y      <<<dim3(16, 32), 256, 0, stream>>>(tokens, embed, D, ws, out);
    k_fc1    <<<512, 256, 0, stream>>>(W1, ws + OFF_YT, ws + OFF_HP);
    k_fc2    <<<128, 256, 0, stream>>>(b1, W2, b2, ws + OFF_HP, out);
}

// Round 3
// 189.734 us; speedup vs baseline: 1.6557x; 1.2027x over previous
//
#include <hip/hip_runtime.h>

#define B_SZ 32
#define L 4096
#define H 512
#define P 384
#define V 32
#define OUT_LEN 16
#define NC 16
#define CHUNK 255
#define T0 4080   // NC*CHUNK

// ---- ws layout (float offsets), with liveness-based aliasing ----
#define OFF_DBL   0           // [P][6] doubles (lbr,lbi,wr,wi,cr,ci) = 4608 floats
#define OFF_LBARF 4608        // [P][2] float Lambda_bar
#define OFF_M     5376        // [V][P][2] token->Bu_bar table      (dead after k_combine)
#define OFF_CT    29952       // [P][2][H] transposed C             (dead after k_y)
#define OFF_PART  423168      // [B][NC][P][2] chunk partials       (dead after k_combine)
#define OFF_XS    816384      // [B][P][16][2] last-16 states       (dead after k_y)
#define OFF_YT    1209600     // [512 r][512 h], r = b*16+l         (live to k_fc1)
#define OFF_HP    29952       // alias over M/CT (dead): [4][512][512] fc1 partials
// ws end = 1471744 floats = 5.89 MB

// K1: 3 independent parts.
//  blocks 0..191   : transpose C -> CT[p][2][H]
//  blocks 192..193 : per-p double constants
//  blocks 194..449 : Yt init = u * D   (k_y atomicAdds onto this)
__global__ __launch_bounds__(256) void k_init(
    const int* __restrict__ tokens, const float* __restrict__ embed,
    const float* __restrict__ Lre, const float* __restrict__ Lim,
    const float* __restrict__ log_step,
    const float* __restrict__ Cre, const float* __restrict__ Cim,
    const float* __restrict__ D, float* __restrict__ ws)
{
    int bx = blockIdx.x, tid = threadIdx.x;
    if (bx < 192) {
        __shared__ float sre[32][33], sim[32][33];
        int tp = bx >> 4, th = bx & 15;          // 12 p-tiles x 16 h-tiles
        int col = tid & 31, r0 = tid >> 5;
        #pragma unroll
        for (int it = 0; it < 4; ++it) {
            int row = r0 + 8 * it;
            int h = th * 32 + row, p = tp * 32 + col;
            sre[col][row] = Cre[h * P + p];
            sim[col][row] = Cim[h * P + p];
        }
        __syncthreads();
        #pragma unroll
        for (int it = 0; it < 4; ++it) {
            int pl = r0 + 8 * it;
            int p = tp * 32 + pl, h = th * 32 + col;
            ws[OFF_CT + (2 * p) * H + h]     = sre[pl][col];
            ws[OFF_CT + (2 * p + 1) * H + h] = sim[pl][col];
        }
    } else if (bx < 194) {
        int p = (bx - 192) * 256 + tid;
        if (p >= P) return;
        double dstep = exp((double)log_step[p]);
        double are = (double)Lre[p] * dstep, aim = (double)Lim[p] * dstep;
        double mag = exp(are);
        double lbr = mag * cos(aim), lbi = mag * sin(aim);
        double wmag = exp((double)CHUNK * are);
        double wang = (double)CHUNK * aim;
        double wr = wmag * cos(wang), wi = wmag * sin(wang);
        double lre = (double)Lre[p], lim = (double)Lim[p];
        double nr = lbr - 1.0, ni = lbi;
        double den = lre * lre + lim * lim;
        double cr = (nr * lre + ni * lim) / den, ci = (ni * lre - nr * lim) / den;
        double* d = (double*)ws + p * 6;
        d[0] = lbr; d[1] = lbi; d[2] = wr; d[3] = wi; d[4] = cr; d[5] = ci;
        ws[OFF_LBARF + 2 * p]     = (float)lbr;
        ws[OFF_LBARF + 2 * p + 1] = (float)lbi;
    } else {
        int idx = (bx - 194) * 256 + tid;        // 65536 threads, 4 floats each
        int r = idx >> 7, hq = idx & 127;        // h = hq*4
        int b = r >> 4, l = r & 15;
        int t = tokens[b * L + T0 + l];
        float4 e = *(const float4*)(embed + t * H + hq * 4);
        float4 dv = *(const float4*)(D + hq * 4);
        float4 o; o.x = e.x * dv.x; o.y = e.y * dv.y; o.z = e.z * dv.z; o.w = e.w * dv.w;
        *(float4*)(ws + OFF_YT + r * H + hq * 4) = o;
    }
}

// K2: M table, one wave per (v,p). 3072 blocks x 256.
__global__ __launch_bounds__(256) void k_mtab(
    const float* __restrict__ embed, const float* __restrict__ Bre,
    const float* __restrict__ Bim, float* __restrict__ ws)
{
    int wid = blockIdx.x * 4 + (threadIdx.x >> 6);
    int lane = threadIdx.x & 63;
    int v = wid / P, p = wid - v * P;
    const float4* ev = (const float4*)(embed + v * H) + lane * 2;
    const float4* br = (const float4*)(Bre + p * H) + lane * 2;
    const float4* bi = (const float4*)(Bim + p * H) + lane * 2;
    float dr = 0.f, di = 0.f;
    #pragma unroll
    for (int q = 0; q < 2; ++q) {
        float4 e = ev[q], r = br[q], i = bi[q];
        dr += r.x * e.x + r.y * e.y + r.z * e.z + r.w * e.w;
        di += i.x * e.x + i.y * e.y + i.z * e.z + i.w * e.w;
    }
    #pragma unroll
    for (int off = 32; off; off >>= 1) {
        dr += __shfl_down(dr, off);
        di += __shfl_down(di, off);
    }
    if (lane == 0) {
        const double* d = (const double*)ws + p * 6;
        double cr = d[4], ci = d[5];
        double mr = cr * (double)dr - ci * (double)di;
        double mi = cr * (double)di + ci * (double)dr;
        ws[OFF_M + (v * P + p) * 2]     = (float)mr;
        ws[OFF_M + (v * P + p) * 2 + 1] = (float)mi;
    }
}

// K3: chunked scan. grid (c*2+ph : 32, b : 32), 192 threads (one p each).
__global__ __launch_bounds__(192) void k_scan(
    const int* __restrict__ tokens, const float* __restrict__ ws,
    float* __restrict__ part)
{
    __shared__ float2 sM[V * 192];
    int x = blockIdx.x, b = blockIdx.y;
    int c = x >> 1, ph = x & 1;
    int tid = threadIdx.x;
    const float2* Mg = (const float2*)(ws + OFF_M);
    #pragma unroll
    for (int v = 0; v < V; ++v)
        sM[v * 192 + tid] = Mg[v * P + ph * 192 + tid];
    int p = ph * 192 + tid;
    float Lr = ws[OFF_LBARF + 2 * p], Li = ws[OFF_LBARF + 2 * p + 1];
    __syncthreads();
    float ar = 0.f, ai = 0.f;
    const int* tk = tokens + b * L + c * CHUNK;
    #pragma unroll 3
    for (int i = 0; i < CHUNK; ++i) {
        int t = tk[i];
        float2 m = sM[t * 192 + tid];
        float nar = fmaf(Lr, ar, fmaf(-Li, ai, m.x));
        float nai = fmaf(Lr, ai, fmaf( Li, ar, m.y));
        ar = nar; ai = nai;
    }
    float* pt = part + ((b * NC + c) * P + p) * 2;
    pt[0] = ar; pt[1] = ai;
}

// K4: combine partials (double) + 16 tail steps. thread = (b,p). 48 blocks.
__global__ __launch_bounds__(256) void k_combine(
    const int* __restrict__ tokens, float* __restrict__ ws)
{
    int id = blockIdx.x * 256 + threadIdx.x;   // exactly 12288
    int b = id / P, p = id - b * P;
    const double* d = (const double*)ws + p * 6;
    double lbr = d[0], lbi = d[1], wr = d[2], wi = d[3];
    double xr = 0.0, xi = 0.0;
    const float* pp = ws + OFF_PART + (b * NC * P + p) * 2;
    #pragma unroll
    for (int c = 0; c < NC; ++c) {
        double pr = (double)pp[c * P * 2], pi = (double)pp[c * P * 2 + 1];
        double tr = wr * xr - wi * xi + pr;
        double ti = wr * xi + wi * xr + pi;
        xr = tr; xi = ti;
    }
    const float* M = ws + OFF_M;
    float* xs = ws + OFF_XS + (b * P + p) * OUT_LEN * 2;
    const int* tk = tokens + b * L + T0;
    #pragma unroll
    for (int j = 0; j < OUT_LEN; ++j) {
        int t = tk[j];
        double mr = (double)M[(t * P + p) * 2], mi = (double)M[(t * P + p) * 2 + 1];
        double tr = lbr * xr - lbi * xi + mr;
        double ti = lbr * xi + lbi * xr + mi;
        xr = tr; xi = ti;
        xs[2 * j] = (float)xr; xs[2 * j + 1] = (float)xi;
    }
}

// K5: Yt += 2*Re(C x). grid (kc*2+hh : 12, b : 32) x 256.
// xs slice staged in LDS; 16 l-accumulators per thread (32 fma per 2 loads).
__global__ __launch_bounds__(256) void k_y(
    float* __restrict__ ws)
{
    __shared__ float sxs[64 * 32];   // 8 KB: xs[b][p0..p0+63][32]
    int x = blockIdx.x, b = blockIdx.y;
    int hh = x & 1, kc = x >> 1;     // kc in [0,6)
    int tid = threadIdx.x;
    int p0 = kc * 64;

    // stage: 2048 floats, 8 per thread (coalesced float4 x2)
    {
        const float4* src = (const float4*)(ws + OFF_XS + b * (P * 32) + p0 * 32);
        float4* dst = (float4*)sxs;
        dst[tid]       = src[tid];
        dst[tid + 256] = src[tid + 256];
    }
    __syncthreads();

    int h = hh * 256 + tid;
    const float* ct = ws + OFF_CT;
    float acc[16];
    #pragma unroll
    for (int i = 0; i < 16; ++i) acc[i] = 0.f;

    #pragma unroll 2
    for (int p = 0; p < 64; ++p) {
        float cre = ct[(2 * (p0 + p)) * H + h];       // coalesced, L2-hot
        float cim = ct[(2 * (p0 + p) + 1) * H + h];
        const float* xv = sxs + p * 32;               // LDS broadcast
        #pragma unroll
        for (int i = 0; i < 16; ++i)
            acc[i] = fmaf(cre, xv[2 * i], fmaf(-cim, xv[2 * i + 1], acc[i]));
    }
    float* yt = ws + OFF_YT + (b * OUT_LEN) * H + h;
    #pragma unroll
    for (int i = 0; i < 16; ++i)
        atomicAdd(&yt[i * H], 2.f * acc[i]);
}

// K6: GEMM1 partials, 4-way k-split, Y-tile staged in LDS.
// grid 512 = (rg:64, jh:2, kc:4), 256 threads. hp[kc][r][j].
__global__ __launch_bounds__(256) void k_fc1(
    const float* __restrict__ W1, const float* __restrict__ ws,
    float* __restrict__ hp)
{
    __shared__ float ys[8][128];     // 4 KB
    int bx = blockIdx.x;
    int rg = bx >> 3, jh = (bx >> 2) & 1, kc = bx & 3;
    int tid = threadIdx.x;
    int j = jh * 256 + tid;
    int r0 = rg * 8, k0 = kc * 128;
    const float* yt = ws + OFF_YT;

    int kk = tid & 127, rr = tid >> 7;   // 2 rows per pass, 4 passes
    #pragma unroll
    for (int it = 0; it < 4; ++it)
        ys[rr + 2 * it][kk] = yt[(r0 + rr + 2 * it) * H + k0 + kk];
    __syncthreads();

    float acc[8] = {0, 0, 0, 0, 0, 0, 0, 0};
    #pragma unroll 4
    for (int k = 0; k < 128; ++k) {
        float w = W1[(k0 + k) * H + j];   // coalesced
        #pragma unroll
        for (int i = 0; i < 8; ++i)
            acc[i] = fmaf(ys[i][k], w, acc[i]);   // LDS broadcast
    }
    #pragma unroll
    for (int i = 0; i < 8; ++i)
        hp[(kc * 512 + r0 + i) * H + j] = acc[i];  // coalesced
}

// K7: one block per output row r. reduce 4 partials + relu -> LDS,
// 8-segment GEMM2 dot, LDS reduce. 512 blocks x 256. Deterministic.
__global__ __launch_bounds__(256) void k_fc2(
    const float* __restrict__ b1, const float* __restrict__ W2,
    const float* __restrict__ b2, const float* __restrict__ hp,
    float* __restrict__ out)
{
    __shared__ float sh[512];
    __shared__ float red[8 * 32];
    int r = blockIdx.x, tid = threadIdx.x;
    #pragma unroll
    for (int half = 0; half < 2; ++half) {
        int j = half * 256 + tid;
        float s = b1[j] + hp[r * H + j] + hp[(512 + r) * H + j]
                        + hp[(1024 + r) * H + j] + hp[(1536 + r) * H + j];
        sh[j] = fmaxf(s, 0.f);
    }
    __syncthreads();
    int seg = tid >> 5, o = tid & 31;
    float acc = 0.f;
    const float* w2 = W2 + seg * 64 * V + o;
    const float* hv = sh + seg * 64;
    #pragma unroll 4
    for (int jj = 0; jj < 64; ++jj)
        acc = fmaf(hv[jj], w2[jj * V], acc);
    red[seg * 32 + o] = acc;
    __syncthreads();
    if (tid < 32) {
        float s = b2[tid];
        #pragma unroll
        for (int ss = 0; ss < 8; ++ss) s += red[ss * 32 + tid];
        out[r * V + tid] = s;
    }
}

extern "C" void kernel_launch(void* const* d_in, const int* in_sizes, int n_in,
                              void* d_out, int out_size, void* d_ws, size_t ws_size,
                              hipStream_t stream)
{
    const int*   tokens = (const int*)d_in[0];
    const float* embed  = (const float*)d_in[1];
    const float* Lre    = (const float*)d_in[2];
    const float* Lim    = (const float*)d_in[3];
    const float* Bre    = (const float*)d_in[4];
    const float* Bim    = (const float*)d_in[5];
    const float* Cre    = (const float*)d_in[6];
    const float* Cim    = (const float*)d_in[7];
    const float* D      = (const float*)d_in[8];
    const float* lstep  = (const float*)d_in[9];
    const float* W1     = (const float*)d_in[10];
    const float* b1     = (const float*)d_in[11];
    const float* W2     = (const float*)d_in[12];
    const float* b2     = (const float*)d_in[13];
    float* out = (float*)d_out;
    float* ws  = (float*)d_ws;

    k_init   <<<450, 256, 0, stream>>>(tokens, embed, Lre, Lim, lstep, Cre, Cim, D, ws);
    k_mtab   <<<3072, 256, 0, stream>>>(embed, Bre, Bim, ws);
    k_scan   <<<dim3(32, 32), 192, 0, stream>>>(tokens, ws, ws + OFF_PART);
    k_combine<<<48, 256, 0, stream>>>(tokens, ws);
    k_y      <<<dim3(12, 32), 256, 0, stream>>>(ws);
    k_fc1    <<<512, 256, 0, stream>>>(W1, ws, ws + OFF_HP);
    k_fc2    <<<512, 256, 0, stream>>>(b1, W2, b2, ws + OFF_HP, out);
}

// Round 4
// 164.857 us; speedup vs baseline: 1.9056x; 1.1509x over previous
//
#include <hip/hip_runtime.h>

#define B_SZ 32
#define L 4096
#define H 512
#define P 384
#define V 32
#define OUT_LEN 16
#define NC 16
#define CHUNK 255
#define T0 4080   // NC*CHUNK

// ---- ws layout (float offsets), liveness-aliased ----
#define OFF_DBL   0           // [P][6] doubles (lbr,lbi,wr,wi,cr,ci)
#define OFF_LBARF 4608        // [P][2] float Lambda_bar
#define OFF_M     5376        // [V][P][2]                      (dead after k_combine)
#define OFF_CT    29952       // [P][2][H] transposed C         (dead after k_y)
#define OFF_PART  423168      // [B][NC][P][2]                  (dead after k_combine)
#define OFF_XS    816384      // [B][P][16][2]                  (dead after k_y)
#define OFF_YT    1209600     // [512 r][512 h], r = b*16+l     (live to k_fc1)
#define OFF_HP    29952       // alias (all dead by fc1): [4][512][512]
// ws end = 1471744 floats = 5.89 MB

// K1: blocks 0..191 transpose C -> CT; blocks 192..193 per-p double constants.
__global__ __launch_bounds__(256) void k_init(
    const float* __restrict__ Lre, const float* __restrict__ Lim,
    const float* __restrict__ log_step,
    const float* __restrict__ Cre, const float* __restrict__ Cim,
    float* __restrict__ ws)
{
    int bx = blockIdx.x, tid = threadIdx.x;
    if (bx < 192) {
        __shared__ float sre[32][33], sim[32][33];
        int tp = bx >> 4, th = bx & 15;
        int col = tid & 31, r0 = tid >> 5;
        #pragma unroll
        for (int it = 0; it < 4; ++it) {
            int row = r0 + 8 * it;
            int h = th * 32 + row, p = tp * 32 + col;
            sre[col][row] = Cre[h * P + p];
            sim[col][row] = Cim[h * P + p];
        }
        __syncthreads();
        #pragma unroll
        for (int it = 0; it < 4; ++it) {
            int pl = r0 + 8 * it;
            int p = tp * 32 + pl, h = th * 32 + col;
            ws[OFF_CT + (2 * p) * H + h]     = sre[pl][col];
            ws[OFF_CT + (2 * p + 1) * H + h] = sim[pl][col];
        }
    } else {
        int p = (bx - 192) * 256 + tid;
        if (p >= P) return;
        double dstep = exp((double)log_step[p]);
        double are = (double)Lre[p] * dstep, aim = (double)Lim[p] * dstep;
        double mag = exp(are);
        double lbr = mag * cos(aim), lbi = mag * sin(aim);
        double wmag = exp((double)CHUNK * are);
        double wang = (double)CHUNK * aim;
        double wr = wmag * cos(wang), wi = wmag * sin(wang);
        double lre = (double)Lre[p], lim = (double)Lim[p];
        double nr = lbr - 1.0, ni = lbi;
        double den = lre * lre + lim * lim;
        double cr = (nr * lre + ni * lim) / den, ci = (ni * lre - nr * lim) / den;
        double* d = (double*)ws + p * 6;
        d[0] = lbr; d[1] = lbi; d[2] = wr; d[3] = wi; d[4] = cr; d[5] = ci;
        ws[OFF_LBARF + 2 * p]     = (float)lbr;
        ws[OFF_LBARF + 2 * p + 1] = (float)lbi;
    }
}

// K2: M table, one wave per (v,p). 3072 blocks x 256.
__global__ __launch_bounds__(256) void k_mtab(
    const float* __restrict__ embed, const float* __restrict__ Bre,
    const float* __restrict__ Bim, float* __restrict__ ws)
{
    int wid = blockIdx.x * 4 + (threadIdx.x >> 6);
    int lane = threadIdx.x & 63;
    int v = wid / P, p = wid - v * P;
    const float4* ev = (const float4*)(embed + v * H) + lane * 2;
    const float4* br = (const float4*)(Bre + p * H) + lane * 2;
    const float4* bi = (const float4*)(Bim + p * H) + lane * 2;
    float dr = 0.f, di = 0.f;
    #pragma unroll
    for (int q = 0; q < 2; ++q) {
        float4 e = ev[q], r = br[q], i = bi[q];
        dr += r.x * e.x + r.y * e.y + r.z * e.z + r.w * e.w;
        di += i.x * e.x + i.y * e.y + i.z * e.z + i.w * e.w;
    }
    #pragma unroll
    for (int off = 32; off; off >>= 1) {
        dr += __shfl_down(dr, off);
        di += __shfl_down(di, off);
    }
    if (lane == 0) {
        const double* d = (const double*)ws + p * 6;
        double cr = d[4], ci = d[5];
        double mr = cr * (double)dr - ci * (double)di;
        double mi = cr * (double)di + ci * (double)dr;
        ws[OFF_M + (v * P + p) * 2]     = (float)mr;
        ws[OFF_M + (v * P + p) * 2 + 1] = (float)mi;
    }
}

// K3: chunked scan. grid (c*2+ph : 32, b : 32), 192 threads. sM stride padded
// to 193 float2: 384%32==0 made every token row alias the same bank pair.
__global__ __launch_bounds__(192) void k_scan(
    const int* __restrict__ tokens, const float* __restrict__ ws,
    float* __restrict__ part)
{
    __shared__ float2 sM[V * 193];   // 49408 B -> still 3 blocks/CU
    int x = blockIdx.x, b = blockIdx.y;
    int c = x >> 1, ph = x & 1;
    int tid = threadIdx.x;
    const float2* Mg = (const float2*)(ws + OFF_M);
    #pragma unroll
    for (int v = 0; v < V; ++v)
        sM[v * 193 + tid] = Mg[v * P + ph * 192 + tid];
    int p = ph * 192 + tid;
    float Lr = ws[OFF_LBARF + 2 * p], Li = ws[OFF_LBARF + 2 * p + 1];
    __syncthreads();
    float ar = 0.f, ai = 0.f;
    const int* tk = tokens + b * L + c * CHUNK;
    #pragma unroll 3
    for (int i = 0; i < CHUNK; ++i) {
        int t = tk[i];
        float2 m = sM[t * 193 + tid];
        float nar = fmaf(Lr, ar, fmaf(-Li, ai, m.x));
        float nai = fmaf(Lr, ai, fmaf( Li, ar, m.y));
        ar = nar; ai = nai;
    }
    float* pt = part + ((b * NC + c) * P + p) * 2;
    pt[0] = ar; pt[1] = ai;
}

// K4: combine partials (double) + 16 tail steps. thread = (b,p). 48 blocks.
__global__ __launch_bounds__(256) void k_combine(
    const int* __restrict__ tokens, float* __restrict__ ws)
{
    int id = blockIdx.x * 256 + threadIdx.x;
    int b = id / P, p = id - b * P;
    const double* d = (const double*)ws + p * 6;
    double lbr = d[0], lbi = d[1], wr = d[2], wi = d[3];
    double xr = 0.0, xi = 0.0;
    const float* pp = ws + OFF_PART + (b * NC * P + p) * 2;
    #pragma unroll
    for (int c = 0; c < NC; ++c) {
        double pr = (double)pp[c * P * 2], pi = (double)pp[c * P * 2 + 1];
        double tr = wr * xr - wi * xi + pr;
        double ti = wr * xi + wi * xr + pi;
        xr = tr; xi = ti;
    }
    const float* M = ws + OFF_M;
    float* xs = ws + OFF_XS + (b * P + p) * OUT_LEN * 2;
    const int* tk = tokens + b * L + T0;
    #pragma unroll
    for (int j = 0; j < OUT_LEN; ++j) {
        int t = tk[j];
        double mr = (double)M[(t * P + p) * 2], mi = (double)M[(t * P + p) * 2 + 1];
        double tr = lbr * xr - lbi * xi + mr;
        double ti = lbr * xi + lbi * xr + mi;
        xr = tr; xi = ti;
        xs[2 * j] = (float)xr; xs[2 * j + 1] = (float)xi;
    }
}

// K5: Yt[r][h] = 2*Re(C x) + u*D, atomic-free.
// grid (hq*2+lh : 16, b : 32) x 256. thread = (h in 64-tile, p-group of 96).
__global__ __launch_bounds__(256) void k_y(
    const int* __restrict__ tokens, const float* __restrict__ embed,
    const float* __restrict__ D, float* __restrict__ ws)
{
    __shared__ float sxs[384 * 16];        // 24 KB: xs[b][p][8 l][2] slice
    __shared__ float sred[4 * 64 * 9];     // padded partials
    int x = blockIdx.x, b = blockIdx.y;
    int lh = x & 1, hq = x >> 1;           // hq in [0,8)
    int tid = threadIdx.x;
    int h0 = hq * 64;

    // stage xs slice: 1536 float4, 6 per thread
    {
        const float4* src = (const float4*)(ws + OFF_XS);
        float4* dst = (float4*)sxs;
        #pragma unroll
        for (int it = 0; it < 6; ++it) {
            int f = tid + 256 * it;
            int p = f >> 2, q = f & 3;
            dst[f] = src[(b * P + p) * 8 + lh * 4 + q];
        }
    }
    __syncthreads();

    int hl = tid & 63, pg = tid >> 6;
    int h = h0 + hl;
    const float* ct = ws + OFF_CT;
    float acc[8];
    #pragma unroll
    for (int i = 0; i < 8; ++i) acc[i] = 0.f;

    int p0 = pg * 96;
    #pragma unroll 2
    for (int pp = 0; pp < 96; ++pp) {
        int p = p0 + pp;
        float cre = ct[(2 * p) * H + h];         // coalesced 64-wide, L2-hot
        float cim = ct[(2 * p + 1) * H + h];
        const float4* xv = (const float4*)(sxs + p * 16);  // wave-uniform broadcast
        float4 x0 = xv[0], x1 = xv[1], x2 = xv[2], x3 = xv[3];
        acc[0] = fmaf(cre, x0.x, fmaf(-cim, x0.y, acc[0]));
        acc[1] = fmaf(cre, x0.z, fmaf(-cim, x0.w, acc[1]));
        acc[2] = fmaf(cre, x1.x, fmaf(-cim, x1.y, acc[2]));
        acc[3] = fmaf(cre, x1.z, fmaf(-cim, x1.w, acc[3]));
        acc[4] = fmaf(cre, x2.x, fmaf(-cim, x2.y, acc[4]));
        acc[5] = fmaf(cre, x2.z, fmaf(-cim, x2.w, acc[5]));
        acc[6] = fmaf(cre, x3.x, fmaf(-cim, x3.y, acc[6]));
        acc[7] = fmaf(cre, x3.z, fmaf(-cim, x3.w, acc[7]));
    }
    #pragma unroll
    for (int i = 0; i < 8; ++i)
        sred[(pg * 64 + hl) * 9 + i] = acc[i];
    __syncthreads();

    // 512 outputs (64 h x 8 l), 2 per thread
    #pragma unroll
    for (int oo = 0; oo < 2; ++oo) {
        int o = tid + 256 * oo;
        int ohl = o & 63, oi = o >> 6;
        float s = sred[ohl * 9 + oi] + sred[(64 + ohl) * 9 + oi]
                + sred[(128 + ohl) * 9 + oi] + sred[(192 + ohl) * 9 + oi];
        int l = lh * 8 + oi;
        int t = tokens[b * L + T0 + l];
        int hh = h0 + ohl;
        ws[OFF_YT + (b * OUT_LEN + l) * H + hh] =
            2.f * s + embed[t * H + hh] * D[hh];
    }
}

// K6: GEMM1 partials, 4-way k-split, depth-2 W1 prefetch, packed ys[k][8r].
// grid 512 = (rg:64, jh:2, kc:4), 256 threads. hp[kc][r][j].
__global__ __launch_bounds__(256) void k_fc1(
    const float* __restrict__ W1, const float* __restrict__ ws,
    float* __restrict__ hp)
{
    __shared__ float ys[128 * 8];    // ys[k][r] packed: 4 KB
    int bx = blockIdx.x;
    int rg = bx >> 3, jh = (bx >> 2) & 1, kc = bx & 3;
    int tid = threadIdx.x;
    int j = jh * 256 + tid;
    int r0 = rg * 8, k0 = kc * 128;
    const float* yt = ws + OFF_YT;

    int kk = tid & 127, rr = tid >> 7;
    #pragma unroll
    for (int it = 0; it < 4; ++it)
        ys[kk * 8 + rr + 2 * it] = yt[(r0 + rr + 2 * it) * H + k0 + kk];
    __syncthreads();

    const float* wp = W1 + k0 * H + j;
    float w0 = wp[0], w1 = wp[H];
    float acc[8] = {0, 0, 0, 0, 0, 0, 0, 0};
    for (int k = 0; k < 128; k += 2) {
        float a0 = w0, a1 = w1;
        if (k + 2 < 128) { w0 = wp[(k + 2) * H]; w1 = wp[(k + 3) * H]; }
        const float4* y0 = (const float4*)(ys + k * 8);
        float4 p0 = y0[0], p1 = y0[1], p2 = y0[2], p3 = y0[3];
        acc[0] = fmaf(p0.x, a0, acc[0]);
        acc[1] = fmaf(p0.y, a0, acc[1]);
        acc[2] = fmaf(p0.z, a0, acc[2]);
        acc[3] = fmaf(p0.w, a0, acc[3]);
        acc[4] = fmaf(p1.x, a0, acc[4]);
        acc[5] = fmaf(p1.y, a0, acc[5]);
        acc[6] = fmaf(p1.z, a0, acc[6]);
        acc[7] = fmaf(p1.w, a0, acc[7]);
        acc[0] = fmaf(p2.x, a1, acc[0]);
        acc[1] = fmaf(p2.y, a1, acc[1]);
        acc[2] = fmaf(p2.z, a1, acc[2]);
        acc[3] = fmaf(p2.w, a1, acc[3]);
        acc[4] = fmaf(p3.x, a1, acc[4]);
        acc[5] = fmaf(p3.y, a1, acc[5]);
        acc[6] = fmaf(p3.z, a1, acc[6]);
        acc[7] = fmaf(p3.w, a1, acc[7]);
    }
    #pragma unroll
    for (int i = 0; i < 8; ++i)
        hp[(kc * 512 + r0 + i) * H + j] = acc[i];
}

// K7: one block per output row r: reduce 4 partials + relu -> LDS, GEMM2.
__global__ __launch_bounds__(256) void k_fc2(
    const float* __restrict__ b1, const float* __restrict__ W2,
    const float* __restrict__ b2, const float* __restrict__ hp,
    float* __restrict__ out)
{
    __shared__ float sh[512];
    __shared__ float red[8 * 32];
    int r = blockIdx.x, tid = threadIdx.x;
    #pragma unroll
    for (int half = 0; half < 2; ++half) {
        int j = half * 256 + tid;
        float s = b1[j] + hp[r * H + j] + hp[(512 + r) * H + j]
                        + hp[(1024 + r) * H + j] + hp[(1536 + r) * H + j];
        sh[j] = fmaxf(s, 0.f);
    }
    __syncthreads();
    int seg = tid >> 5, o = tid & 31;
    float acc = 0.f;
    const float* w2 = W2 + seg * 64 * V + o;
    const float* hv = sh + seg * 64;
    #pragma unroll 4
    for (int jj = 0; jj < 64; ++jj)
        acc = fmaf(hv[jj], w2[jj * V], acc);
    red[seg * 32 + o] = acc;
    __syncthreads();
    if (tid < 32) {
        float s = b2[tid];
        #pragma unroll
        for (int ss = 0; ss < 8; ++ss) s += red[ss * 32 + tid];
        out[r * V + tid] = s;
    }
}

extern "C" void kernel_launch(void* const* d_in, const int* in_sizes, int n_in,
                              void* d_out, int out_size, void* d_ws, size_t ws_size,
                              hipStream_t stream)
{
    const int*   tokens = (const int*)d_in[0];
    const float* embed  = (const float*)d_in[1];
    const float* Lre    = (const float*)d_in[2];
    const float* Lim    = (const float*)d_in[3];
    const float* Bre    = (const float*)d_in[4];
    const float* Bim    = (const float*)d_in[5];
    const float* Cre    = (const float*)d_in[6];
    const float* Cim    = (const float*)d_in[7];
    const float* D      = (const float*)d_in[8];
    const float* lstep  = (const float*)d_in[9];
    const float* W1     = (const float*)d_in[10];
    const float* b1     = (const float*)d_in[11];
    const float* W2     = (const float*)d_in[12];
    const float* b2     = (const float*)d_in[13];
    float* out = (float*)d_out;
    float* ws  = (float*)d_ws;

    k_init   <<<194, 256, 0, stream>>>(Lre, Lim, lstep, Cre, Cim, ws);
    k_mtab   <<<3072, 256, 0, stream>>>(embed, Bre, Bim, ws);
    k_scan   <<<dim3(32, 32), 192, 0, stream>>>(tokens, ws, ws + OFF_PART);
    k_combine<<<48, 256, 0, stream>>>(tokens, ws);
    k_y      <<<dim3(16, 32), 256, 0, stream>>>(tokens, embed, D, ws);
    k_fc1    <<<512, 256, 0, stream>>>(W1, ws, ws + OFF_HP);
    k_fc2    <<<512, 256, 0, stream>>>(b1, W2, b2, ws + OFF_HP, out);
}

// Round 5
// 144.778 us; speedup vs baseline: 2.1698x; 1.1387x over previous
//
#include <hip/hip_runtime.h>

#define B_SZ 32
#define L 4096
#define H 512
#define P 384
#define V 32
#define OUT_LEN 16
#define NC 16
#define CHUNK 255
#define T0 4080   // NC*CHUNK

// ---- ws layout (float offsets), no aliasing (ws is 268 MB) ----
#define OFF_DBL   0           // [P][6] doubles (lbr,lbi,wr,wi,cr,ci)
#define OFF_LBARF 4608        // [P][2] float Lambda_bar
#define OFF_M     5376        // [V][P][2] UNSCALED dot table M0 (coef factored out)
#define OFF_CT    423168      // wait  -- see below
#undef  OFF_CT
#define OFF_CT    29952       // [P][2][H] transposed C
#define OFF_PART  423168      // [B][NC][P][2] chunk z-partials
#define OFF_YT    816384      // [512 r][512 h], r = b*16+l
#define OFF_HP    1078528     // [4][512][512] fc1 k-split partials
// end = 2127104 floats = 8.5 MB

// K1 "prep" — three independent parts, no internal deps:
//  blocks 0..1     : per-p double constants (Lbar, W=Lbar^CHUNK, coef)
//  blocks 2..193   : transpose C -> CT[p][2][H]
//  blocks 194..3265: M0[v][p] = <embed[v], Bc[p]>  (pure fp32, one wave each)
__global__ __launch_bounds__(256) void k_prep(
    const float* __restrict__ embed, const float* __restrict__ Bre,
    const float* __restrict__ Bim,
    const float* __restrict__ Lre, const float* __restrict__ Lim,
    const float* __restrict__ log_step,
    const float* __restrict__ Cre, const float* __restrict__ Cim,
    float* __restrict__ ws)
{
    int bx = blockIdx.x, tid = threadIdx.x;
    if (bx < 2) {
        int p = bx * 256 + tid;
        if (p >= P) return;
        double dstep = exp((double)log_step[p]);
        double are = (double)Lre[p] * dstep, aim = (double)Lim[p] * dstep;
        double mag = exp(are);
        double lbr = mag * cos(aim), lbi = mag * sin(aim);
        double wmag = exp((double)CHUNK * are);
        double wang = (double)CHUNK * aim;
        double wr = wmag * cos(wang), wi = wmag * sin(wang);
        double lre = (double)Lre[p], lim = (double)Lim[p];
        double nr = lbr - 1.0, ni = lbi;
        double den = lre * lre + lim * lim;
        double cr = (nr * lre + ni * lim) / den, ci = (ni * lre - nr * lim) / den;
        double* d = (double*)ws + p * 6;
        d[0] = lbr; d[1] = lbi; d[2] = wr; d[3] = wi; d[4] = cr; d[5] = ci;
        ws[OFF_LBARF + 2 * p]     = (float)lbr;
        ws[OFF_LBARF + 2 * p + 1] = (float)lbi;
    } else if (bx < 194) {
        __shared__ float sre[32][33], sim[32][33];
        int bxx = bx - 2;
        int tp = bxx >> 4, th = bxx & 15;        // 12 p-tiles x 16 h-tiles
        int col = tid & 31, r0 = tid >> 5;
        #pragma unroll
        for (int it = 0; it < 4; ++it) {
            int row = r0 + 8 * it;
            int h = th * 32 + row, p = tp * 32 + col;
            sre[col][row] = Cre[h * P + p];
            sim[col][row] = Cim[h * P + p];
        }
        __syncthreads();
        #pragma unroll
        for (int it = 0; it < 4; ++it) {
            int pl = r0 + 8 * it;
            int p = tp * 32 + pl, h = th * 32 + col;
            ws[OFF_CT + (2 * p) * H + h]     = sre[pl][col];
            ws[OFF_CT + (2 * p + 1) * H + h] = sim[pl][col];
        }
    } else {
        int wid = (bx - 194) * 4 + (tid >> 6);   // [0, 12288)
        int lane = tid & 63;
        int v = wid / P, p = wid - v * P;
        const float4* ev = (const float4*)(embed + v * H) + lane * 2;
        const float4* br = (const float4*)(Bre + p * H) + lane * 2;
        const float4* bi = (const float4*)(Bim + p * H) + lane * 2;
        float dr = 0.f, di = 0.f;
        #pragma unroll
        for (int q = 0; q < 2; ++q) {
            float4 e = ev[q], r = br[q], i = bi[q];
            dr += r.x * e.x + r.y * e.y + r.z * e.z + r.w * e.w;
            di += i.x * e.x + i.y * e.y + i.z * e.z + i.w * e.w;
        }
        #pragma unroll
        for (int off = 32; off; off >>= 1) {
            dr += __shfl_down(dr, off);
            di += __shfl_down(di, off);
        }
        if (lane == 0) {
            ws[OFF_M + (v * P + p) * 2]     = dr;   // UNSCALED
            ws[OFF_M + (v * P + p) * 2 + 1] = di;
        }
    }
}

// K2: chunked z-scan over M0. grid (c*2+ph : 32, b : 32), 192 threads.
__global__ __launch_bounds__(192) void k_scan(
    const int* __restrict__ tokens, const float* __restrict__ ws,
    float* __restrict__ part)
{
    __shared__ float2 sM[V * 193];   // padded stride
    int x = blockIdx.x, b = blockIdx.y;
    int c = x >> 1, ph = x & 1;
    int tid = threadIdx.x;
    const float2* Mg = (const float2*)(ws + OFF_M);
    #pragma unroll
    for (int v = 0; v < V; ++v)
        sM[v * 193 + tid] = Mg[v * P + ph * 192 + tid];
    int p = ph * 192 + tid;
    float Lr = ws[OFF_LBARF + 2 * p], Li = ws[OFF_LBARF + 2 * p + 1];
    __syncthreads();
    float ar = 0.f, ai = 0.f;
    const int* tk = tokens + b * L + c * CHUNK;
    #pragma unroll 3
    for (int i = 0; i < CHUNK; ++i) {
        int t = tk[i];
        float2 m = sM[t * 193 + tid];
        float nar = fmaf(Lr, ar, fmaf(-Li, ai, m.x));
        float nai = fmaf(Lr, ai, fmaf( Li, ar, m.y));
        ar = nar; ai = nai;
    }
    float* pt = part + ((b * NC + c) * P + p) * 2;
    pt[0] = ar; pt[1] = ai;
}

// K3: fused combine + y. grid (hq*2+lh : 16, b : 32) x 384 threads.
// Phase A (thread=p): double combine of 16 chunk partials + 16 tail steps,
//   apply coef (double), write this block's 8 l-states to LDS.
// Phase B (thread=(hl,pg)): 8 l-accs over 64 p, CT coalesced + LDS broadcast.
// Phase C: LDS reduce over 6 p-groups, add u*D, store Yt.
__global__ __launch_bounds__(384) void k_y(
    const int* __restrict__ tokens, const float* __restrict__ embed,
    const float* __restrict__ D, float* __restrict__ ws)
{
    __shared__ float sxs[P * 16];        // 24 KB
    __shared__ float sred[384 * 9];      // 13.5 KB
    int x = blockIdx.x, b = blockIdx.y;
    int lh = x & 1, hq = x >> 1;         // hq in [0,8)
    int tid = threadIdx.x;
    int h0 = hq * 64;

    {   // ---- phase A: combine (redundant x8 per (b,lh), ~cheap DP) ----
        int p = tid;                     // 384 threads = P
        const double* d = (const double*)ws + p * 6;
        double lbr = d[0], lbi = d[1], wr = d[2], wi = d[3], cr = d[4], ci = d[5];
        double zr = 0.0, zi = 0.0;
        const float* pp = ws + OFF_PART + (b * NC * P + p) * 2;
        #pragma unroll
        for (int c = 0; c < NC; ++c) {
            double pr = (double)pp[c * P * 2], pi = (double)pp[c * P * 2 + 1];
            double tr = wr * zr - wi * zi + pr;
            double ti = wr * zi + wi * zr + pi;
            zr = tr; zi = ti;
        }
        const float* M0 = ws + OFF_M;
        const int* tk = tokens + b * L + T0;
        #pragma unroll
        for (int j = 0; j < OUT_LEN; ++j) {
            int t = tk[j];
            double mr = (double)M0[(t * P + p) * 2];
            double mi = (double)M0[(t * P + p) * 2 + 1];
            double tr = lbr * zr - lbi * zi + mr;
            double ti = lbr * zi + lbi * zr + mi;
            zr = tr; zi = ti;
            if ((j >> 3) == lh) {
                int jj = j & 7;
                sxs[p * 16 + 2 * jj]     = (float)(cr * zr - ci * zi);
                sxs[p * 16 + 2 * jj + 1] = (float)(cr * zi + ci * zr);
            }
        }
    }
    __syncthreads();

    // ---- phase B ----
    int hl = tid & 63, pg = tid >> 6;    // pg in [0,6)
    int h = h0 + hl;
    const float* ct = ws + OFF_CT;
    float acc[8];
    #pragma unroll
    for (int i = 0; i < 8; ++i) acc[i] = 0.f;
    int p0 = pg * 64;
    #pragma unroll 2
    for (int ppp = 0; ppp < 64; ++ppp) {
        int p = p0 + ppp;
        float cre = ct[(2 * p) * H + h];       // coalesced 64-wide
        float cim = ct[(2 * p + 1) * H + h];
        const float4* xv = (const float4*)(sxs + p * 16);  // wave-uniform
        float4 x0 = xv[0], x1 = xv[1], x2 = xv[2], x3 = xv[3];
        acc[0] = fmaf(cre, x0.x, fmaf(-cim, x0.y, acc[0]));
        acc[1] = fmaf(cre, x0.z, fmaf(-cim, x0.w, acc[1]));
        acc[2] = fmaf(cre, x1.x, fmaf(-cim, x1.y, acc[2]));
        acc[3] = fmaf(cre, x1.z, fmaf(-cim, x1.w, acc[3]));
        acc[4] = fmaf(cre, x2.x, fmaf(-cim, x2.y, acc[4]));
        acc[5] = fmaf(cre, x2.z, fmaf(-cim, x2.w, acc[5]));
        acc[6] = fmaf(cre, x3.x, fmaf(-cim, x3.y, acc[6]));
        acc[7] = fmaf(cre, x3.z, fmaf(-cim, x3.w, acc[7]));
    }
    #pragma unroll
    for (int i = 0; i < 8; ++i)
        sred[(pg * 64 + hl) * 9 + i] = acc[i];
    __syncthreads();

    // ---- phase C: 512 outputs, reduce 6 p-groups ----
    #pragma unroll
    for (int oo = 0; oo < 2; ++oo) {
        int o = tid + 384 * oo;
        if (o < 512) {
            int ohl = o & 63, oi = o >> 6;
            float s = 0.f;
            #pragma unroll
            for (int g = 0; g < 6; ++g)
                s += sred[(g * 64 + ohl) * 9 + oi];
            int l = lh * 8 + oi;
            int t = tokens[b * L + T0 + l];
            int hh = h0 + ohl;
            ws[OFF_YT + (b * OUT_LEN + l) * H + hh] =
                2.f * s + embed[t * H + hh] * D[hh];
        }
    }
}

// K4: GEMM1 partials, 4-way k-split, DEPTH-8 W1 prefetch, packed ys[k][8r].
// grid 512 = (rg:64, jh:2, kc:4), 256 threads. hp[kc][r][j].
__global__ __launch_bounds__(256) void k_fc1(
    const float* __restrict__ W1, const float* __restrict__ ws,
    float* __restrict__ hp)
{
    __shared__ float ys[128 * 8];
    int bx = blockIdx.x;
    int rg = bx >> 3, jh = (bx >> 2) & 1, kc = bx & 3;
    int tid = threadIdx.x;
    int j = jh * 256 + tid;
    int r0 = rg * 8, k0 = kc * 128;
    const float* yt = ws + OFF_YT;

    int kk = tid & 127, rr = tid >> 7;
    #pragma unroll
    for (int it = 0; it < 4; ++it)
        ys[kk * 8 + rr + 2 * it] = yt[(r0 + rr + 2 * it) * H + k0 + kk];
    __syncthreads();

    const float* wp = W1 + k0 * H + j;
    float wreg[8];
    #pragma unroll
    for (int u = 0; u < 8; ++u) wreg[u] = wp[u * H];
    float acc[8] = {0, 0, 0, 0, 0, 0, 0, 0};
    for (int kb = 0; kb < 128; kb += 8) {
        float cur[8];
        #pragma unroll
        for (int u = 0; u < 8; ++u) cur[u] = wreg[u];
        if (kb + 8 < 128) {
            #pragma unroll
            for (int u = 0; u < 8; ++u) wreg[u] = wp[(kb + 8 + u) * H];
        }
        #pragma unroll
        for (int u = 0; u < 8; ++u) {
            const float4* y0 = (const float4*)(ys + (kb + u) * 8);
            float4 p0 = y0[0], p1 = y0[1];
            float a = cur[u];
            acc[0] = fmaf(p0.x, a, acc[0]);
            acc[1] = fmaf(p0.y, a, acc[1]);
            acc[2] = fmaf(p0.z, a, acc[2]);
            acc[3] = fmaf(p0.w, a, acc[3]);
            acc[4] = fmaf(p1.x, a, acc[4]);
            acc[5] = fmaf(p1.y, a, acc[5]);
            acc[6] = fmaf(p1.z, a, acc[6]);
            acc[7] = fmaf(p1.w, a, acc[7]);
        }
    }
    #pragma unroll
    for (int i = 0; i < 8; ++i)
        hp[(kc * 512 + r0 + i) * H + j] = acc[i];
}

// K5: per-row reduce + relu + GEMM2. 512 blocks x 256. 4-acc unroll.
__global__ __launch_bounds__(256) void k_fc2(
    const float* __restrict__ b1, const float* __restrict__ W2,
    const float* __restrict__ b2, const float* __restrict__ hp,
    float* __restrict__ out)
{
    __shared__ float sh[512];
    __shared__ float red[8 * 32];
    int r = blockIdx.x, tid = threadIdx.x;
    #pragma unroll
    for (int half = 0; half < 2; ++half) {
        int j = half * 256 + tid;
        float s = b1[j] + hp[r * H + j] + hp[(512 + r) * H + j]
                        + hp[(1024 + r) * H + j] + hp[(1536 + r) * H + j];
        sh[j] = fmaxf(s, 0.f);
    }
    __syncthreads();
    int seg = tid >> 5, o = tid & 31;
    const float* w2 = W2 + seg * 64 * V + o;
    const float* hv = sh + seg * 64;
    float a0 = 0.f, a1 = 0.f, a2 = 0.f, a3 = 0.f;
    #pragma unroll
    for (int q = 0; q < 16; ++q) {
        a0 = fmaf(hv[q],      w2[q * V],        a0);
        a1 = fmaf(hv[16 + q], w2[(16 + q) * V], a1);
        a2 = fmaf(hv[32 + q], w2[(32 + q) * V], a2);
        a3 = fmaf(hv[48 + q], w2[(48 + q) * V], a3);
    }
    red[seg * 32 + o] = (a0 + a1) + (a2 + a3);
    __syncthreads();
    if (tid < 32) {
        float s = b2[tid];
        #pragma unroll
        for (int ss = 0; ss < 8; ++ss) s += red[ss * 32 + tid];
        out[r * V + tid] = s;
    }
}

extern "C" void kernel_launch(void* const* d_in, const int* in_sizes, int n_in,
                              void* d_out, int out_size, void* d_ws, size_t ws_size,
                              hipStream_t stream)
{
    const int*   tokens = (const int*)d_in[0];
    const float* embed  = (const float*)d_in[1];
    const float* Lre    = (const float*)d_in[2];
    const float* Lim    = (const float*)d_in[3];
    const float* Bre    = (const float*)d_in[4];
    const float* Bim    = (const float*)d_in[5];
    const float* Cre    = (const float*)d_in[6];
    const float* Cim    = (const float*)d_in[7];
    const float* D      = (const float*)d_in[8];
    const float* lstep  = (const float*)d_in[9];
    const float* W1     = (const float*)d_in[10];
    const float* b1     = (const float*)d_in[11];
    const float* W2     = (const float*)d_in[12];
    const float* b2     = (const float*)d_in[13];
    float* out = (float*)d_out;
    float* ws  = (float*)d_ws;

    k_prep <<<3266, 256, 0, stream>>>(embed, Bre, Bim, Lre, Lim, lstep, Cre, Cim, ws);
    k_scan <<<dim3(32, 32), 192, 0, stream>>>(tokens, ws, ws + OFF_PART);
    k_y    <<<dim3(16, 32), 384, 0, stream>>>(tokens, embed, D, ws);
    k_fc1  <<<512, 256, 0, stream>>>(W1, ws, ws + OFF_HP);
    k_fc2  <<<512, 256, 0, stream>>>(b1, W2, b2, ws + OFF_HP, out);
}